// Round 9
// baseline (109.381 us; speedup 1.0000x reference)
//
#include <hip/hip_runtime.h>
#include <stdint.h>

#define D_DIM 128
#define NROW 8192          // 2B
#define L2EPS 1e-12f
#define SCALE_A 14.426950408889634f  // 10/ln2: MFMA out = sim*10/ln2 = exp2 arg
#define LN2 0.6931471805599453f
#define NPART 96           // 32 row-partial slots (by cc) + 64 col-partial slots (by rb)

typedef __attribute__((ext_vector_type(4))) int   i32x4;
typedef __attribute__((ext_vector_type(8))) int   i32x8;
typedef __attribute__((ext_vector_type(4))) float f32x4;

#define AS1 __attribute__((address_space(1)))
#define AS3 __attribute__((address_space(3)))

static __device__ inline void gload_lds16(const void* g, void* l) {
    __builtin_amdgcn_global_load_lds((const AS1 uint32_t*)g, (AS3 uint32_t*)l, 16, 0, 0);
}

static __device__ inline i32x8 cat8(i32x4 lo, i32x4 hi) {
    i32x8 r;
    r[0] = lo[0]; r[1] = lo[1]; r[2] = lo[2]; r[3] = lo[3];
    r[4] = hi[0]; r[5] = hi[1]; r[6] = hi[2]; r[7] = hi[3];
    return r;
}

// K1: L2-normalize rows of [x_i; x_j]; emit fp8 e4m3 z8 (B) and z8s (A,
// pre-scaled by 10/ln2 so MFMA output is the exp2 argument). Also zero the
// partial array and scalar accumulators.
__global__ __launch_bounds__(256) void k_normalize(
        const float* __restrict__ xi, const float* __restrict__ xj,
        uint8_t* __restrict__ z8, uint8_t* __restrict__ z8s,
        float* __restrict__ part, float* __restrict__ pos_acc,
        float* __restrict__ logsum) {
    const int wave = threadIdx.x >> 6;
    const int lane = threadIdx.x & 63;
    const int row = blockIdx.x * 4 + wave;
    const float* src = (row < 4096) ? (xi + (size_t)row * D_DIM)
                                    : (xj + (size_t)(row - 4096) * D_DIM);
    float2 v = *(const float2*)(src + lane * 2);
    float ss = v.x * v.x + v.y * v.y;
#pragma unroll
    for (int m = 32; m >= 1; m >>= 1) ss += __shfl_xor(ss, m, 64);
    const float scale = 1.0f / fmaxf(sqrtf(ss), L2EPS);
    const float scale_a = scale * SCALE_A;
    const int pk_b = __builtin_amdgcn_cvt_pk_fp8_f32(v.x * scale,   v.y * scale,   0, false);
    const int pk_a = __builtin_amdgcn_cvt_pk_fp8_f32(v.x * scale_a, v.y * scale_a, 0, false);
    *(ushort*)(z8  + (size_t)row * D_DIM + lane * 2) = (ushort)pk_b;
    *(ushort*)(z8s + (size_t)row * D_DIM + lane * 2) = (ushort)pk_a;

    // Zero partials: 96*8192 floats over 2048*256 threads (2 strides).
    const int tid = blockIdx.x * 256 + threadIdx.x;
#pragma unroll
    for (int k = 0; k < 2; k++) {
        const int idx = tid + k * (2048 * 256);
        if (idx < NPART * NROW) part[idx] = 0.0f;
    }
    if (blockIdx.x == 0 && threadIdx.x == 0) { pos_acc[0] = 0.0f; logsum[0] = 0.0f; }
}

// K2 (symmetric): 1056 upper-triangle tiles (rb=0..63 x cc=rb/2..31); tile =
// rows [rb*128,+128) x cols [cc*256,+256) of sim*10/ln2, via ONE
// mfma_scale_16x16x128 per (i,j) sub-tile. Each exp credits BOTH denom[row]
// (slot cc, lane-reduce) and denom[col] (slot 32+rb, quad+LDS reduce) --
// halves the exp work. Diag tiles mask c>r; odd-band diag tiles skip their
// below-diagonal half. Positives counted once (tiles rb<32, cc=16+rb/2),
// doubled in the combine. B tile LDS-resident (one barrier in the K-loop's
// place); A frags direct from L2-resident z8s.
__global__ __launch_bounds__(256) void k_gemm(
        const uint8_t* __restrict__ z8, const uint8_t* __restrict__ z8s,
        float* __restrict__ part, float* __restrict__ pos_acc) {
    __shared__ __align__(16) uint8_t lds[32768];   // 256 cols x 128 B fp8

    const int t = threadIdx.x;
    const int wave = t >> 6, lane = t & 63;
    const int quad = lane >> 4, lc = lane & 15;

    // bid -> (rb, cc) in the upper-triangle enumeration.
    int rem = blockIdx.x, rb = 0;
    while (rem >= 32 - (rb >> 1)) { rem -= 32 - (rb >> 1); rb++; }
    const int cc = (rb >> 1) + rem;
    const int rowbase = rb * 128;
    const int colbase = cc * 256;

    // DMA B tile: slot s (16B units) holds row r=s>>3, unit g=(s&7)^(r&7).
    {
        const uint8_t* zb = z8 + (size_t)colbase * D_DIM;
#pragma unroll
        for (int q = 0; q < 8; q++) {
            const int s = q * 256 + t;
            const int r = s >> 3;
            const int g = (s & 7) ^ (r & 7);
            gload_lds16(zb + (size_t)r * D_DIM + g * 16, &lds[s * 16]);
        }
    }

    // A fragments: 32 B of row (rowbase+wave*32+i*16+lc), bytes [quad*32,+32).
    i32x8 afr[2];
    {
        const uint8_t* pa = z8s + (size_t)(rowbase + wave * 32 + lc) * D_DIM + quad * 32;
#pragma unroll
        for (int i = 0; i < 2; i++) {
            i32x4 lo = *(const i32x4*)(pa + i * 16 * D_DIM);
            i32x4 hi = *(const i32x4*)(pa + i * 16 * D_DIM + 16);
            afr[i] = cat8(lo, hi);
        }
    }

    asm volatile("s_waitcnt vmcnt(0)" ::: "memory");
    __syncthreads();   // B tile resident; loop below is barrier-free

    const bool diagblk = (cc == (rb >> 1));
    const int  jd_lo = (rb & 1) ? 8 : 0;   // diag-mask window [jd_lo, jd_lo+8)
    const bool posblk = (rb < 32) && (cc == 16 + (rb >> 1));
    const int  j0p = (rb & 1) * 8 + wave * 2;

    float rs[2][4] = {{0.f,0.f,0.f,0.f},{0.f,0.f,0.f,0.f}};
    float cs[16];
#pragma unroll
    for (int j = 0; j < 16; j++) cs[j] = 0.f;
    float posp = 0.f;
    const int rgbase = rowbase + wave * 32 + quad * 4;   // + i*16 + r

#pragma unroll
    for (int j = 0; j < 16; j++) {
        if (diagblk && (rb & 1) && j < 8) continue;   // fully below diagonal

        const int rowb = (j * 16 + lc) * D_DIM;
        i32x4 blo = *(const i32x4*)&lds[rowb + (((quad * 2)     ^ (lc & 7)) * 16)];
        i32x4 bhi = *(const i32x4*)&lds[rowb + (((quad * 2 + 1) ^ (lc & 7)) * 16)];
        const i32x8 bfr = cat8(blo, bhi);

        f32x4 z4 = {0.f, 0.f, 0.f, 0.f};
        f32x4 a0 = __builtin_amdgcn_mfma_scale_f32_16x16x128_f8f6f4(
                       afr[0], bfr, z4, 0, 0, 0, 127, 0, 127);
        f32x4 a1 = __builtin_amdgcn_mfma_scale_f32_16x16x128_f8f6f4(
                       afr[1], bfr, z4, 0, 0, 0, 127, 0, 127);

        if (diagblk && j >= jd_lo && j < jd_lo + 8) {
            // 128x128 diagonal block: keep strictly-upper elements only.
            const int cg = colbase + j * 16 + lc;
#pragma unroll
            for (int i = 0; i < 2; i++)
#pragma unroll
                for (int r = 0; r < 4; r++) {
                    const float s = (i ? a1 : a0)[r];
                    const int rg = rgbase + i * 16 + r;
                    const float e = (cg > rg) ? exp2f(s) : 0.f;
                    rs[i][r] += e;
                    cs[j] += e;
                }
        } else if (posblk && (unsigned)(j - j0p) < 2u) {
            const int cg = colbase + j * 16 + lc;
#pragma unroll
            for (int i = 0; i < 2; i++)
#pragma unroll
                for (int r = 0; r < 4; r++) {
                    const float s = (i ? a1 : a0)[r];
                    const float e = exp2f(s);
                    const int rg = rgbase + i * 16 + r;
                    if (cg == rg + 4096) posp += s;   // positive (scaled)
                    rs[i][r] += e;
                    cs[j] += e;
                }
        } else {   // hot path
#pragma unroll
            for (int r = 0; r < 4; r++) {
                const float e0 = exp2f(a0[r]);
                const float e1 = exp2f(a1[r]);
                rs[0][r] += e0;
                rs[1][r] += e1;
                cs[j] += e0 + e1;
            }
        }
    }

    // Row partials -> slot cc (reduce over the 16 col-lanes).
#pragma unroll
    for (int i = 0; i < 2; i++)
#pragma unroll
        for (int r = 0; r < 4; r++) {
            float v = rs[i][r];
            v += __shfl_xor(v, 1, 64);
            v += __shfl_xor(v, 2, 64);
            v += __shfl_xor(v, 4, 64);
            v += __shfl_xor(v, 8, 64);
            if (lc == 0)
                part[(size_t)cc * NROW + rgbase + i * 16 + r] = v;
        }

    // Col partials -> slot 32+rb: quad-reduce, then cross-wave LDS reduce.
#pragma unroll
    for (int j = 0; j < 16; j++) {
        cs[j] += __shfl_xor(cs[j], 16, 64);
        cs[j] += __shfl_xor(cs[j], 32, 64);
    }
    __syncthreads();                    // all B reads done; reuse LDS
    float* colred = (float*)lds;        // [4][256]
    if (quad == 0) {
#pragma unroll
        for (int j = 0; j < 16; j++)
            colred[wave * 256 + j * 16 + lc] = cs[j];
    }
    __syncthreads();
    if (t < 256) {
        const float v = colred[t] + colred[256 + t] + colred[512 + t] + colred[768 + t];
        part[(size_t)(32 + rb) * NROW + colbase + t] = v;
    }

    if (posblk) {
#pragma unroll
        for (int m = 32; m >= 1; m >>= 1) posp += __shfl_xor(posp, m, 64);
        if (lane == 0) atomicAdd(pos_acc, posp);
    }
}

// K3: one row per thread: denom = sum of 96 partial slots; log; reduce; atomic.
__global__ __launch_bounds__(256) void k_logsum(
        const float* __restrict__ part, float* __restrict__ logsum) {
    const int row = blockIdx.x * 256 + threadIdx.x;
    float d = 0.f;
#pragma unroll
    for (int p = 0; p < NPART; p++) d += part[(size_t)p * NROW + row];
    float v = __logf(d);
#pragma unroll
    for (int m = 32; m >= 1; m >>= 1) v += __shfl_xor(v, m, 64);
    if ((threadIdx.x & 63) == 0) atomicAdd(logsum, v);
}

// K4: combine. pos_acc = sum over the 4096 unique positive pairs of
// sim*10/ln2; each pair appears twice in the reference -> factor 2*ln2.
__global__ void k_combine(const float* __restrict__ logsum,
                          const float* __restrict__ pos_acc,
                          float* __restrict__ out) {
    out[0] = (logsum[0] - pos_acc[0] * 2.0f * LN2) / (float)NROW;
}

extern "C" void kernel_launch(void* const* d_in, const int* in_sizes, int n_in,
                              void* d_out, int out_size, void* d_ws, size_t ws_size,
                              hipStream_t stream) {
    const float* xi = (const float*)d_in[0];
    const float* xj = (const float*)d_in[1];
    uint8_t* z8  = (uint8_t*)d_ws;                               // 1 MB fp8
    uint8_t* z8s = z8 + (size_t)NROW * D_DIM;                    // 1 MB fp8 (scaled)
    float* part = (float*)(z8s + (size_t)NROW * D_DIM);          // 96 x 8192 f32
    float* pos_acc = part + (size_t)NPART * NROW;
    float* logsum = pos_acc + 1;
    float* out = (float*)d_out;

    hipLaunchKernelGGL(k_normalize, dim3(NROW / 4), dim3(256), 0, stream,
                       xi, xj, z8, z8s, part, pos_acc, logsum);
    hipLaunchKernelGGL(k_gemm, dim3(1056), dim3(256), 0, stream,
                       z8, z8s, part, pos_acc);
    hipLaunchKernelGGL(k_logsum, dim3(NROW / 256), dim3(256), 0, stream,
                       part, logsum);
    hipLaunchKernelGGL(k_combine, dim3(1), dim3(1), 0, stream,
                       logsum, pos_acc, out);
}

// Round 10
// 100.997 us; speedup vs baseline: 1.0830x; 1.0830x over previous
//
#include <hip/hip_runtime.h>
#include <stdint.h>

#define D_DIM 128
#define NROW 8192          // 2B
#define L2EPS 1e-12f
#define SCALE_A 14.426950408889634f  // 10/ln2: MFMA out = sim*10/ln2 = exp2 arg
#define LN2 0.6931471805599453f
#define NPART 66           // row-credit slots m=0..32, col-credit slots 33+m

typedef __attribute__((ext_vector_type(4))) int   i32x4;
typedef __attribute__((ext_vector_type(8))) int   i32x8;
typedef __attribute__((ext_vector_type(4))) float f32x4;

#define AS1 __attribute__((address_space(1)))
#define AS3 __attribute__((address_space(3)))

static __device__ inline void gload_lds16(const void* g, void* l) {
    __builtin_amdgcn_global_load_lds((const AS1 uint32_t*)g, (AS3 uint32_t*)l, 16, 0, 0);
}

static __device__ inline i32x8 cat8(i32x4 lo, i32x4 hi) {
    i32x8 r;
    r[0] = lo[0]; r[1] = lo[1]; r[2] = lo[2]; r[3] = lo[3];
    r[4] = hi[0]; r[5] = hi[1]; r[6] = hi[2]; r[7] = hi[3];
    return r;
}

// K1: L2-normalize rows of [x_i; x_j]; emit fp8 e4m3 z8 (B operand) and
// z8s = fp8(z * 10/ln2) (A operand -> MFMA output is the exp2 argument).
__global__ __launch_bounds__(256) void k_normalize(
        const float* __restrict__ xi, const float* __restrict__ xj,
        uint8_t* __restrict__ z8, uint8_t* __restrict__ z8s,
        float* __restrict__ pos_acc, float* __restrict__ logsum) {
    const int wave = threadIdx.x >> 6;
    const int lane = threadIdx.x & 63;
    const int row = blockIdx.x * 4 + wave;
    const float* src = (row < 4096) ? (xi + (size_t)row * D_DIM)
                                    : (xj + (size_t)(row - 4096) * D_DIM);
    float2 v = *(const float2*)(src + lane * 2);
    float ss = v.x * v.x + v.y * v.y;
#pragma unroll
    for (int m = 32; m >= 1; m >>= 1) ss += __shfl_xor(ss, m, 64);
    const float scale = 1.0f / fmaxf(sqrtf(ss), L2EPS);
    const float scale_a = scale * SCALE_A;
    const int pk_b = __builtin_amdgcn_cvt_pk_fp8_f32(v.x * scale,   v.y * scale,   0, false);
    const int pk_a = __builtin_amdgcn_cvt_pk_fp8_f32(v.x * scale_a, v.y * scale_a, 0, false);
    *(ushort*)(z8  + (size_t)row * D_DIM + lane * 2) = (ushort)pk_b;
    *(ushort*)(z8s + (size_t)row * D_DIM + lane * 2) = (ushort)pk_a;

    if (blockIdx.x == 0 && threadIdx.x == 0) { pos_acc[0] = 0.0f; logsum[0] = 0.0f; }
}

// K2 (circulant-symmetric): block (m = bid>>6 in 0..32, rb = bid&63) computes
// the 128x128 tile rows [rb*128,+128) x cols [((rb+m)%64)*128,+128) with one
// mfma_scale_16x16x128 per (i,j) sub-tile. Every exp credits BOTH denom[row]
// (slot m) and denom[col] (slot 33+m) -> each unordered pair computed once.
//   m = 0 : in-band diagonal tile -> keep strictly-upper (c>r) only.
//   m = 32: distance-4096 tiles, enumerated from both sides -> e *= 0.5;
//           tile diagonal = the positive pairs (posp += s).
// Block-uniform modes: three separate j-loops, no per-j branching.
// B tile (16 KB fp8, XOR-swizzled) LDS-resident after ONE barrier.
__global__ __launch_bounds__(256) void k_gemm(
        const uint8_t* __restrict__ z8, const uint8_t* __restrict__ z8s,
        float* __restrict__ part, float* __restrict__ pos_acc) {
    __shared__ __align__(16) uint8_t lds[16384];   // 128 cols x 128 B fp8

    const int t = threadIdx.x;
    const int wave = t >> 6, lane = t & 63;
    const int quad = lane >> 4, lc = lane & 15;

    const int m  = blockIdx.x >> 6;     // 0..32
    const int rb = blockIdx.x & 63;     // 0..63
    const int cc = (rb + m) & 63;
    const int rowbase = rb * 128;
    const int colbase = cc * 128;

    // DMA B tile: 1024 16B slots; slot s holds row r=s>>3, unit g=(s&7)^(r&7).
    {
        const uint8_t* zb = z8 + (size_t)colbase * D_DIM;
#pragma unroll
        for (int q = 0; q < 4; q++) {
            const int s = q * 256 + t;
            const int r = s >> 3;
            const int g = (s & 7) ^ (r & 7);
            gload_lds16(zb + (size_t)r * D_DIM + g * 16, &lds[s * 16]);
        }
    }

    // A fragments: 32 B of row (rowbase + wave*32 + i*16 + lc), bytes [quad*32,+32).
    i32x8 afr[2];
    {
        const uint8_t* pa = z8s + (size_t)(rowbase + wave * 32 + lc) * D_DIM + quad * 32;
#pragma unroll
        for (int i = 0; i < 2; i++) {
            i32x4 lo = *(const i32x4*)(pa + i * 16 * D_DIM);
            i32x4 hi = *(const i32x4*)(pa + i * 16 * D_DIM + 16);
            afr[i] = cat8(lo, hi);
        }
    }

    asm volatile("s_waitcnt vmcnt(0)" ::: "memory");
    __syncthreads();   // B tile resident; j-loops below are barrier-free

    float rs[2][4] = {{0.f,0.f,0.f,0.f},{0.f,0.f,0.f,0.f}};
    float cs[8] = {0.f,0.f,0.f,0.f,0.f,0.f,0.f,0.f};
    float posp = 0.f;
    const int rl0 = wave * 32 + quad * 4;   // local row = rl0 + i*16 + r

    // One (i,j) MFMA pair for column sub-tile j.
#define MFMA_J(j, A0, A1)                                                     \
    i32x4 blo, bhi; {                                                         \
        const int rowb = ((j) * 16 + lc) * D_DIM;                             \
        blo = *(const i32x4*)&lds[rowb + (((quad * 2)     ^ (lc & 7)) * 16)]; \
        bhi = *(const i32x4*)&lds[rowb + (((quad * 2 + 1) ^ (lc & 7)) * 16)]; \
    }                                                                         \
    const i32x8 bfr = cat8(blo, bhi);                                         \
    f32x4 z4 = {0.f, 0.f, 0.f, 0.f};                                          \
    f32x4 A0 = __builtin_amdgcn_mfma_scale_f32_16x16x128_f8f6f4(              \
                   afr[0], bfr, z4, 0, 0, 0, 127, 0, 127);                    \
    f32x4 A1 = __builtin_amdgcn_mfma_scale_f32_16x16x128_f8f6f4(              \
                   afr[1], bfr, z4, 0, 0, 0, 127, 0, 127);

    if (m == 0) {            // diagonal tile: strictly-upper only
#pragma unroll
        for (int j = 0; j < 8; j++) {
            MFMA_J(j, a0, a1)
            const int cl = j * 16 + lc;
#pragma unroll
            for (int i = 0; i < 2; i++)
#pragma unroll
                for (int r = 0; r < 4; r++) {
                    const float s = (i ? a1 : a0)[r];
                    const int rl = rl0 + i * 16 + r;
                    const float e = (cl > rl) ? exp2f(s) : 0.f;
                    rs[i][r] += e;
                    cs[j] += e;
                }
        }
    } else if (m == 32) {    // both-sides tiles: halve; tile diag = positives
#pragma unroll
        for (int j = 0; j < 8; j++) {
            MFMA_J(j, a0, a1)
            const int cl = j * 16 + lc;
#pragma unroll
            for (int i = 0; i < 2; i++)
#pragma unroll
                for (int r = 0; r < 4; r++) {
                    const float s = (i ? a1 : a0)[r];
                    const float e = 0.5f * exp2f(s);
                    const int rl = rl0 + i * 16 + r;
                    if (cl == rl) posp += s;   // positive pair (scaled)
                    rs[i][r] += e;
                    cs[j] += e;
                }
        }
    } else {                 // hot path: 31/33 of blocks
#pragma unroll
        for (int j = 0; j < 8; j++) {
            MFMA_J(j, a0, a1)
#pragma unroll
            for (int r = 0; r < 4; r++) {
                const float e0 = exp2f(a0[r]);
                const float e1 = exp2f(a1[r]);
                rs[0][r] += e0;
                rs[1][r] += e1;
                cs[j] += e0 + e1;
            }
        }
    }
#undef MFMA_J

    // Row credits -> slot m (reduce over the 16 col-lanes).
#pragma unroll
    for (int i = 0; i < 2; i++)
#pragma unroll
        for (int r = 0; r < 4; r++) {
            float v = rs[i][r];
            v += __shfl_xor(v, 1, 64);
            v += __shfl_xor(v, 2, 64);
            v += __shfl_xor(v, 4, 64);
            v += __shfl_xor(v, 8, 64);
            if (lc == 0)
                part[(size_t)m * NROW + rowbase + rl0 + i * 16 + r] = v;
        }

    // Col credits -> slot 33+m: quad-reduce, then cross-wave LDS reduce.
#pragma unroll
    for (int j = 0; j < 8; j++) {
        cs[j] += __shfl_xor(cs[j], 16, 64);
        cs[j] += __shfl_xor(cs[j], 32, 64);
    }
    __syncthreads();                    // all B reads done; reuse LDS
    float* colred = (float*)lds;        // [4][128]
    if (quad == 0) {
#pragma unroll
        for (int j = 0; j < 8; j++)
            colred[wave * 128 + j * 16 + lc] = cs[j];
    }
    __syncthreads();
    if (t < 128) {
        const float v = colred[t] + colred[128 + t] + colred[256 + t] + colred[384 + t];
        part[(size_t)(33 + m) * NROW + colbase + t] = v;
    }

    if (m == 32) {
#pragma unroll
        for (int mm = 32; mm >= 1; mm >>= 1) posp += __shfl_xor(posp, mm, 64);
        if (lane == 0) atomicAdd(pos_acc, posp);
    }
}

// K3: one row per thread: denom = sum of 66 partial slots; log; reduce; atomic.
__global__ __launch_bounds__(256) void k_logsum(
        const float* __restrict__ part, float* __restrict__ logsum) {
    const int row = blockIdx.x * 256 + threadIdx.x;
    float d = 0.f;
#pragma unroll
    for (int p = 0; p < NPART; p++) d += part[(size_t)p * NROW + row];
    float v = __logf(d);
#pragma unroll
    for (int m = 32; m >= 1; m >>= 1) v += __shfl_xor(v, m, 64);
    if ((threadIdx.x & 63) == 0) atomicAdd(logsum, v);
}

// K4: combine. pos_acc = sum of scaled sim over BOTH appearances of each
// positive pair (matches the reference's sim_ij + sim_ji) -> factor ln2 only.
__global__ void k_combine(const float* __restrict__ logsum,
                          const float* __restrict__ pos_acc,
                          float* __restrict__ out) {
    out[0] = (logsum[0] - pos_acc[0] * LN2) / (float)NROW;
}

extern "C" void kernel_launch(void* const* d_in, const int* in_sizes, int n_in,
                              void* d_out, int out_size, void* d_ws, size_t ws_size,
                              hipStream_t stream) {
    const float* xi = (const float*)d_in[0];
    const float* xj = (const float*)d_in[1];
    uint8_t* z8  = (uint8_t*)d_ws;                               // 1 MB fp8
    uint8_t* z8s = z8 + (size_t)NROW * D_DIM;                    // 1 MB fp8 (scaled)
    float* part = (float*)(z8s + (size_t)NROW * D_DIM);          // 66 x 8192 f32
    float* pos_acc = part + (size_t)NPART * NROW;
    float* logsum = pos_acc + 1;
    float* out = (float*)d_out;

    hipLaunchKernelGGL(k_normalize, dim3(NROW / 4), dim3(256), 0, stream,
                       xi, xj, z8, z8s, pos_acc, logsum);
    hipLaunchKernelGGL(k_gemm, dim3(33 * 64), dim3(256), 0, stream,
                       z8, z8s, part, pos_acc);
    hipLaunchKernelGGL(k_logsum, dim3(NROW / 256), dim3(256), 0, stream,
                       part, logsum);
    hipLaunchKernelGGL(k_combine, dim3(1), dim3(1), 0, stream,
                       logsum, pos_acc, out);
}

// Round 11
// 84.785 us; speedup vs baseline: 1.2901x; 1.1912x over previous
//
#include <hip/hip_runtime.h>
#include <stdint.h>

#define D_DIM 128
#define NROW 8192          // 2B
#define L2EPS 1e-12f
#define SCALE_A 14.426950408889634f  // 10/ln2: MFMA out = sim*10/ln2 = exp2 arg
#define LN2 0.6931471805599453f
#define NPART 50           // row slots 0..16 (mb), col slots 17..48, diag col 49

typedef __attribute__((ext_vector_type(4))) int   i32x4;
typedef __attribute__((ext_vector_type(8))) int   i32x8;
typedef __attribute__((ext_vector_type(4))) float f32x4;

#define AS1 __attribute__((address_space(1)))
#define AS3 __attribute__((address_space(3)))

static __device__ inline void gload_lds16(const void* g, void* l) {
    __builtin_amdgcn_global_load_lds((const AS1 uint32_t*)g, (AS3 uint32_t*)l, 16, 0, 0);
}

static __device__ inline i32x8 cat8(i32x4 lo, i32x4 hi) {
    i32x8 r;
    r[0] = lo[0]; r[1] = lo[1]; r[2] = lo[2]; r[3] = lo[3];
    r[4] = hi[0]; r[5] = hi[1]; r[6] = hi[2]; r[7] = hi[3];
    return r;
}

// K1: L2-normalize rows of [x_i; x_j]; emit fp8 e4m3 z8 (B operand) and
// z8s = fp8(z * 10/ln2) (A operand -> MFMA output is the exp2 argument).
__global__ __launch_bounds__(256) void k_normalize(
        const float* __restrict__ xi, const float* __restrict__ xj,
        uint8_t* __restrict__ z8, uint8_t* __restrict__ z8s,
        float* __restrict__ pos_acc, float* __restrict__ logsum,
        unsigned* __restrict__ done_ct) {
    const int wave = threadIdx.x >> 6;
    const int lane = threadIdx.x & 63;
    const int row = blockIdx.x * 4 + wave;
    const float* src = (row < 4096) ? (xi + (size_t)row * D_DIM)
                                    : (xj + (size_t)(row - 4096) * D_DIM);
    float2 v = *(const float2*)(src + lane * 2);
    float ss = v.x * v.x + v.y * v.y;
#pragma unroll
    for (int m = 32; m >= 1; m >>= 1) ss += __shfl_xor(ss, m, 64);
    const float scale = 1.0f / fmaxf(sqrtf(ss), L2EPS);
    const float scale_a = scale * SCALE_A;
    const int pk_b = __builtin_amdgcn_cvt_pk_fp8_f32(v.x * scale,   v.y * scale,   0, false);
    const int pk_a = __builtin_amdgcn_cvt_pk_fp8_f32(v.x * scale_a, v.y * scale_a, 0, false);
    *(ushort*)(z8  + (size_t)row * D_DIM + lane * 2) = (ushort)pk_b;
    *(ushort*)(z8s + (size_t)row * D_DIM + lane * 2) = (ushort)pk_a;

    if (blockIdx.x == 0 && threadIdx.x == 0) {
        pos_acc[0] = 0.0f; logsum[0] = 0.0f; done_ct[0] = 0u;
    }
}

// K2 (paired-circulant symmetric, r8-sized blocks): block (mb=bid>>6, rb=bid&63).
//  mb<16 : rows band rb x col bands c1=(rb+2mb+1)%64, c2=(rb+2mb+2)%64
//          (128x256 tile, 32 MFMA). Distances 1..31 covered once (full e);
//          mb==15's second half = distance 32, double-enumerated -> e*=0.5,
//          sub-tile diagonal = positive pairs (both directions accumulated).
//  mb==16: diagonal tile rb x rb, strictly-upper (c>r) only.
// Each e credits denom[row] (slot mb) and denom[col] (slots 17+2mb / +1;
// diag col slot 49). All 50 slots single-writer & fully covered -> no atomics,
// no zeroing. B bands LDS-resident (XOR swizzle) after ONE barrier.
__global__ __launch_bounds__(256) void k_gemm(
        const uint8_t* __restrict__ z8, const uint8_t* __restrict__ z8s,
        float* __restrict__ part, float* __restrict__ pos_acc) {
    __shared__ __align__(16) uint8_t lds[32768];   // 256 B-rows x 128 B fp8

    const int t = threadIdx.x;
    const int wave = t >> 6, lane = t & 63;
    const int quad = lane >> 4, lc = lane & 15;

    const int mb = blockIdx.x >> 6;     // 0..16
    const int rb = blockIdx.x & 63;
    const int rowbase = rb * 128;
    const bool diag = (mb == 16);
    const int c1 = diag ? rb : (rb + 2 * mb + 1) & 63;
    const int c2 = (rb + 2 * mb + 2) & 63;          // unused when diag

    // Stage B: band c1 -> lds rows 0..127, band c2 -> rows 128..255.
    // Slot s: row r=s>>3, slot-unit u holds global 16B-unit u^(r&7).
    {
        const uint8_t* zb1 = z8 + (size_t)c1 * 128 * D_DIM;
#pragma unroll
        for (int q = 0; q < 4; q++) {
            const int s = q * 256 + t;
            const int r = s >> 3;
            const int g = (s & 7) ^ (r & 7);
            gload_lds16(zb1 + (size_t)r * D_DIM + g * 16, &lds[s * 16]);
        }
        if (!diag) {
            const uint8_t* zb2 = z8 + (size_t)c2 * 128 * D_DIM;
#pragma unroll
            for (int q = 0; q < 4; q++) {
                const int s = q * 256 + t;
                const int r = s >> 3;
                const int g = (s & 7) ^ (r & 7);
                gload_lds16(zb2 + (size_t)r * D_DIM + g * 16, &lds[16384 + s * 16]);
            }
        }
    }

    // A fragments: 32 B of row (rowbase + wave*32 + i*16 + lc), bytes [quad*32,+32).
    i32x8 afr[2];
    {
        const uint8_t* pa = z8s + (size_t)(rowbase + wave * 32 + lc) * D_DIM + quad * 32;
#pragma unroll
        for (int i = 0; i < 2; i++) {
            i32x4 lo = *(const i32x4*)(pa + i * 16 * D_DIM);
            i32x4 hi = *(const i32x4*)(pa + i * 16 * D_DIM + 16);
            afr[i] = cat8(lo, hi);
        }
    }

    asm volatile("s_waitcnt vmcnt(0)" ::: "memory");
    __syncthreads();   // B resident; j-loops below are barrier-free

    float rs[2][4] = {{0.f,0.f,0.f,0.f},{0.f,0.f,0.f,0.f}};
    float cs[16];
#pragma unroll
    for (int j = 0; j < 16; j++) cs[j] = 0.f;
    float posp = 0.f;
    const int rl0 = wave * 32 + quad * 4;   // local row = rl0 + i*16 + r

    // B-row jr = j*16+lc; jr&7 == lc&7, so read slot-units (quad*2..+1)^(lc&7).
#define MFMA_J(j, A0, A1)                                                     \
    i32x4 blo, bhi; {                                                         \
        const int rowb = ((j) * 16 + lc) * D_DIM;                             \
        blo = *(const i32x4*)&lds[rowb + (((quad * 2)     ^ (lc & 7)) * 16)]; \
        bhi = *(const i32x4*)&lds[rowb + (((quad * 2 + 1) ^ (lc & 7)) * 16)]; \
    }                                                                         \
    const i32x8 bfr = cat8(blo, bhi);                                         \
    f32x4 z4 = {0.f, 0.f, 0.f, 0.f};                                          \
    f32x4 A0 = __builtin_amdgcn_mfma_scale_f32_16x16x128_f8f6f4(              \
                   afr[0], bfr, z4, 0, 0, 0, 127, 0, 127);                    \
    f32x4 A1 = __builtin_amdgcn_mfma_scale_f32_16x16x128_f8f6f4(              \
                   afr[1], bfr, z4, 0, 0, 0, 127, 0, 127);

    if (!diag) {
#pragma unroll
        for (int j = 0; j < 8; j++) {        // band c1: always full credit
            MFMA_J(j, a0, a1)
#pragma unroll
            for (int r = 0; r < 4; r++) {
                const float e0 = exp2f(a0[r]);
                const float e1 = exp2f(a1[r]);
                rs[0][r] += e0;
                rs[1][r] += e1;
                cs[j] += e0 + e1;
            }
        }
        if (mb < 15) {                        // band c2: full credit
#pragma unroll
            for (int j = 8; j < 16; j++) {
                MFMA_J(j, a0, a1)
#pragma unroll
                for (int r = 0; r < 4; r++) {
                    const float e0 = exp2f(a0[r]);
                    const float e1 = exp2f(a1[r]);
                    rs[0][r] += e0;
                    rs[1][r] += e1;
                    cs[j] += e0 + e1;
                }
            }
        } else {                              // distance-32: halve; diag = positives
#pragma unroll
            for (int j = 8; j < 16; j++) {
                MFMA_J(j, a0, a1)
                const int clb = (j - 8) * 16 + lc;   // band-local col
#pragma unroll
                for (int i = 0; i < 2; i++)
#pragma unroll
                    for (int r = 0; r < 4; r++) {
                        const float s = (i ? a1 : a0)[r];
                        const float e = 0.5f * exp2f(s);
                        if (clb == rl0 + i * 16 + r) posp += s;
                        rs[i][r] += e;
                        cs[j] += e;
                    }
            }
        }
    } else {                                  // diagonal tile: strictly upper
#pragma unroll
        for (int j = 0; j < 8; j++) {
            MFMA_J(j, a0, a1)
            const int cl = j * 16 + lc;
#pragma unroll
            for (int i = 0; i < 2; i++)
#pragma unroll
                for (int r = 0; r < 4; r++) {
                    const float s = (i ? a1 : a0)[r];
                    const float e = (cl > rl0 + i * 16 + r) ? exp2f(s) : 0.f;
                    rs[i][r] += e;
                    cs[j] += e;
                }
        }
    }
#undef MFMA_J

    // Row credits -> slot mb (reduce over the 16 col-lanes).
#pragma unroll
    for (int i = 0; i < 2; i++)
#pragma unroll
        for (int r = 0; r < 4; r++) {
            float v = rs[i][r];
            v += __shfl_xor(v, 1, 64);
            v += __shfl_xor(v, 2, 64);
            v += __shfl_xor(v, 4, 64);
            v += __shfl_xor(v, 8, 64);
            if (lc == 0)
                part[(size_t)mb * NROW + rowbase + rl0 + i * 16 + r] = v;
        }

    // Col credits: quad-reduce, cross-wave LDS reduce, one store per col.
#pragma unroll
    for (int j = 0; j < 16; j++) {
        cs[j] += __shfl_xor(cs[j], 16, 64);
        cs[j] += __shfl_xor(cs[j], 32, 64);
    }
    __syncthreads();                    // all B reads done; reuse LDS
    float* colred = (float*)lds;        // [4][256]
    if (quad == 0) {
#pragma unroll
        for (int j = 0; j < 16; j++)
            colred[wave * 256 + j * 16 + lc] = cs[j];
    }
    __syncthreads();
    if (t < 256) {
        const float v = colred[t] + colred[256 + t] + colred[512 + t] + colred[768 + t];
        if (!diag) {
            const int slot = 17 + 2 * mb + (t >> 7);
            const int band = (t < 128) ? c1 : c2;
            part[(size_t)slot * NROW + band * 128 + (t & 127)] = v;
        } else if (t < 128) {
            part[(size_t)49 * NROW + c1 * 128 + t] = v;
        }
    }

    if (mb == 15) {
#pragma unroll
        for (int mm = 32; mm >= 1; mm >>= 1) posp += __shfl_xor(posp, mm, 64);
        if (lane == 0) atomicAdd(pos_acc, posp);
    }
}

// K3 (fused logsum + combine): 32 blocks, one row per thread; last block
// (atomic counter) writes the final loss. pos_acc holds scaled sim over both
// appearances of each positive pair -> factor ln2.
__global__ __launch_bounds__(256) void k_logsum(
        const float* __restrict__ part, float* __restrict__ pos_acc,
        float* __restrict__ logsum, unsigned* __restrict__ done_ct,
        float* __restrict__ out) {
    const int row = blockIdx.x * 256 + threadIdx.x;
    float d = 0.f;
#pragma unroll
    for (int p = 0; p < NPART; p++) d += part[(size_t)p * NROW + row];
    float v = __logf(d);
#pragma unroll
    for (int m = 32; m >= 1; m >>= 1) v += __shfl_xor(v, m, 64);
    if ((threadIdx.x & 63) == 0) atomicAdd(logsum, v);
    __threadfence();
    __syncthreads();
    if (threadIdx.x == 0) {
        const unsigned prev = atomicAdd(done_ct, 1u);
        if (prev == gridDim.x - 1) {          // last block: all adds visible
            __threadfence();
            const float ls = atomicAdd(logsum, 0.0f);
            const float pp = atomicAdd(pos_acc, 0.0f);
            out[0] = (ls - pp * LN2) / (float)NROW;
        }
    }
}

extern "C" void kernel_launch(void* const* d_in, const int* in_sizes, int n_in,
                              void* d_out, int out_size, void* d_ws, size_t ws_size,
                              hipStream_t stream) {
    const float* xi = (const float*)d_in[0];
    const float* xj = (const float*)d_in[1];
    uint8_t* z8  = (uint8_t*)d_ws;                               // 1 MB fp8
    uint8_t* z8s = z8 + (size_t)NROW * D_DIM;                    // 1 MB fp8 (scaled)
    float* part = (float*)(z8s + (size_t)NROW * D_DIM);          // 50 x 8192 f32
    float* pos_acc = part + (size_t)NPART * NROW;
    float* logsum = pos_acc + 1;
    unsigned* done_ct = (unsigned*)(logsum + 1);
    float* out = (float*)d_out;

    hipLaunchKernelGGL(k_normalize, dim3(NROW / 4), dim3(256), 0, stream,
                       xi, xj, z8, z8s, pos_acc, logsum, done_ct);
    hipLaunchKernelGGL(k_gemm, dim3(17 * 64), dim3(256), 0, stream,
                       z8, z8s, part, pos_acc);
    hipLaunchKernelGGL(k_logsum, dim3(NROW / 256), dim3(256), 0, stream,
                       part, pos_acc, logsum, done_ct, out);
}